// Round 9
// baseline (442.269 us; speedup 1.0000x reference)
//
#include <hip/hip_runtime.h>
#include <stdint.h>
#include <stddef.h>

#define HIDDEN 2048
#define INTER  5632
#define TOKENS 4096   // B*S = 2*2048
#define BKD    128    // f16 K-tile (down GEMM)  -> 2 half-tiles of 128B rows, 44 iters
#define BKI    128    // i8 K-tile (gateup GEMM) -> 128B rows, 16 iters

typedef __attribute__((ext_vector_type(8))) _Float16 f16x8;
typedef __attribute__((ext_vector_type(4))) _Float16 f16x4;
typedef __attribute__((ext_vector_type(4))) float    f32x4;
typedef __attribute__((ext_vector_type(4))) int      i32x4;

// 128B-row LDS swizzle, period-8 row rotation: global segment q of row r lives
// at slot r*8 + ((q + r) & 7).  ds_read_b128 conflict unit is an 8-lane phase
// (8 x 16B = all 32 banks): fixed q -> 8 consecutive rows hit 8 DISTINCT
// bank-quads -> conflict-free (HW-verified: SQ_LDS_BANK_CONFLICT = 0, R0-R7).
__device__ __forceinline__ int swz8(int row, int q) {
    return row * 8 + ((q + row) & 7);
}

#define GLDS16(g, l) __builtin_amdgcn_global_load_lds( \
    (__attribute__((address_space(1))) void*)(g), \
    (__attribute__((address_space(3))) void*)(l), 16, 0, 0)

__device__ __forceinline__ int pack4i8(float4 f) {
    return ((int)(signed char)(int)f.x & 255)
         | (((int)(signed char)(int)f.y & 255) << 8)
         | (((int)(signed char)(int)f.z & 255) << 16)
         | (((int)(signed char)(int)f.w) << 24);
}

// ---------------------------------------------------------------------------
// fused prepass (R7 version).  MEASUREMENT NOTE (R9): this kernel is
// idempotent (pure deterministic transform of const inputs into workspace),
// so kernel_launch runs it 3x this round to measure its duration P via
// total-time subtraction: dur_us - 371.2 = 2*(P + launch_gap).  The ~187us
// pool (total - gateup - down) has resisted attribution for 8 rounds; this
// splits it into prepass-vs-harness conclusively.
// ---------------------------------------------------------------------------
__global__ __launch_bounds__(256)
void prepass(const float* __restrict__ x,
             const float4* __restrict__ gw, const float4* __restrict__ uw,
             const float4* __restrict__ dw,
             int8_t* __restrict__ xq, float* __restrict__ xs,
             int* __restrict__ go, int* __restrict__ uo,
             _Float16* __restrict__ dno) {
    const int tid = threadIdx.x;
    if (blockIdx.x < 1024) {
        // ---- token quantization: wave-per-token ----
        const int wave = tid >> 6;
        const int lane = tid & 63;
        const int t    = blockIdx.x * 4 + wave;
        const float4* row = (const float4*)(x + (size_t)t * HIDDEN); // 512 f4
        float4 v[8];
        #pragma unroll
        for (int j = 0; j < 8; ++j) v[j] = row[lane + 64 * j];
        float m = 0.0f;
        #pragma unroll
        for (int j = 0; j < 8; ++j) {
            m = fmaxf(m, fmaxf(fmaxf(fabsf(v[j].x), fabsf(v[j].y)),
                               fmaxf(fabsf(v[j].z), fabsf(v[j].w))));
        }
        #pragma unroll
        for (int off = 32; off; off >>= 1)
            m = fmaxf(m, __shfl_xor(m, off, 64));
        m = fmaxf(m, 1e-20f);
        if (lane == 0) xs[t] = m * (1.0f / 127.0f);
        const float inv = 127.0f / m;
        int* oq = (int*)(xq + (size_t)t * HIDDEN);
        #pragma unroll
        for (int j = 0; j < 8; ++j) {
            float4 f = v[j];
            f.x *= inv; f.y *= inv; f.z *= inv; f.w *= inv;
            float4 r;
            r.x = rintf(f.x); r.y = rintf(f.y); r.z = rintf(f.z); r.w = rintf(f.w);
            oq[lane + 64 * j] = pack4i8(r);
        }
        return;
    }
    // ---- weight conversion: 64B units ----
    const int NA = INTER * HIDDEN / 16;   // 720896
    const int NC = INTER * HIDDEN / 8;    // 1441792
    const int stride = 2048 * 256;
    for (int u = (blockIdx.x - 1024) * 256 + tid; u < 2 * NA + NC; u += stride) {
        if (u < 2 * NA) {
            const bool is_g = u < NA;
            const int j = is_g ? u : u - NA;
            const float4* src = (is_g ? gw : uw) + (size_t)j * 4;
            float4 f0 = src[0], f1 = src[1], f2 = src[2], f3 = src[3];
            int4 p;
            p.x = pack4i8(f0); p.y = pack4i8(f1);
            p.z = pack4i8(f2); p.w = pack4i8(f3);
            ((int4*)(is_g ? go : uo))[j] = p;
        } else {
            const int j = u - 2 * NA;
            const float4* src = dw + (size_t)j * 2;
            float4 a = src[0], b = src[1];
            f16x8 o;
            o[0] = (_Float16)a.x; o[1] = (_Float16)a.y;
            o[2] = (_Float16)a.z; o[3] = (_Float16)a.w;
            o[4] = (_Float16)b.x; o[5] = (_Float16)b.y;
            o[6] = (_Float16)b.z; o[7] = (_Float16)b.w;
            *(f16x8*)(dno + (size_t)j * 8) = o;
        }
    }
}

// ---------------------------------------------------------------------------
// GEMM1 fused (i8): H = silu(G*xs*gs) * (U*xs*us)  (fp16 out)
// R4/R7-exact config (measured 100.8us): 128x128 tile, 256 thr, BKI=128 (16
// K-iters), LDS 48KB, 2 blocks/CU, R0 2-barrier compiler schedule, swz8
// layout, XCD-chunked grid (1408 = 8*176).
// ---------------------------------------------------------------------------
__global__ __launch_bounds__(256, 2)
void gemm_gateup(const int8_t* __restrict__ Xq,
                 const int8_t* __restrict__ Wg,
                 const int8_t* __restrict__ Wu,
                 const float* __restrict__ xs,
                 const float* __restrict__ gs,
                 const float* __restrict__ us,
                 _Float16* __restrict__ Hm) {
    __shared__ int8_t As [128 * BKI];
    __shared__ int8_t Bgs[128 * BKI];
    __shared__ int8_t Bus[128 * BKI];

    const int pid   = (blockIdx.x % 8) * 176 + blockIdx.x / 8;
    const int local = pid % (16 * 44);
    const int bm    = ((pid / (16 * 44)) * 16 + (local & 15)) * 128;
    const int bn    = (local >> 4) * 128;

    const int tid  = threadIdx.x;
    const int lane = tid & 63;
    const int wave = tid >> 6;
    const int wm   = (wave >> 1) * 64;
    const int wn   = (wave & 1) * 64;
    const int l15  = lane & 15;
    const int lq   = lane >> 4;

    int rowA[4], sgA[4];
    #pragma unroll
    for (int j = 0; j < 4; ++j) {
        const int f = tid + 256 * j;
        rowA[j] = f >> 3;
        sgA[j]  = (((f & 7) - rowA[j]) & 7) * 16;
    }

    i32x4 accg[4][4] = {};
    i32x4 accu[4][4] = {};

    for (int k0 = 0; k0 < HIDDEN; k0 += BKI) {
        #pragma unroll
        for (int j = 0; j < 4; ++j) {
            const int f = tid + 256 * j;
            const int8_t* pX = Xq + (size_t)(bm + rowA[j]) * HIDDEN + k0 + sgA[j];
            const int8_t* pG = Wg + (size_t)(bn + rowA[j]) * HIDDEN + k0 + sgA[j];
            const int8_t* pU = Wu + (size_t)(bn + rowA[j]) * HIDDEN + k0 + sgA[j];
            GLDS16(pX, &As [f * 16]);
            GLDS16(pG, &Bgs[f * 16]);
            GLDS16(pU, &Bus[f * 16]);
        }
        __syncthreads();

        #pragma unroll
        for (int ks = 0; ks < 2; ++ks) {
            const int q = ks * 4 + lq;
            i32x4 a[4];
            #pragma unroll
            for (int im = 0; im < 4; ++im)
                a[im] = *(const i32x4*)&As[swz8(wm + im * 16 + l15, q) * 16];
            #pragma unroll
            for (int jn = 0; jn < 4; ++jn) {
                i32x4 bg = *(const i32x4*)&Bgs[swz8(wn + jn * 16 + l15, q) * 16];
                i32x4 bu = *(const i32x4*)&Bus[swz8(wn + jn * 16 + l15, q) * 16];
                #pragma unroll
                for (int im = 0; im < 4; ++im) {
                    accg[im][jn] = __builtin_amdgcn_mfma_i32_16x16x64_i8(a[im], bg, accg[im][jn], 0, 0, 0);
                    accu[im][jn] = __builtin_amdgcn_mfma_i32_16x16x64_i8(a[im], bu, accu[im][jn], 0, 0, 0);
                }
            }
        }
        __syncthreads();
    }

    #pragma unroll
    for (int jn = 0; jn < 4; ++jn) {
        const int col = bn + wn + jn * 16 + l15;
        const float sg = gs[col];
        const float su = us[col];
        #pragma unroll
        for (int im = 0; im < 4; ++im) {
            const int rbase = bm + wm + im * 16 + lq * 4;
            #pragma unroll
            for (int r = 0; r < 4; ++r) {
                const int row = rbase + r;
                const float st = xs[row];
                float g = (float)accg[im][jn][r] * st * sg;
                float u = (float)accu[im][jn][r] * st * su;
                float h = (g / (1.0f + __expf(-g))) * u;
                Hm[(size_t)row * INTER + col] = (_Float16)h;
            }
        }
    }
}

// ---------------------------------------------------------------------------
// GEMM2 (fp16): out = (H @ Wd^T) * down_s  (fp32 out)
// R6/R7-exact config (inferred ~83us): 128x128 tile, 256 thr, BKD=128 via two
// swz8 half-tiles per matrix -> 44 K-iters, LDS 64KB, 2 blocks/CU.
// Grid 512 = 8*64, XCD-chunked.
// ---------------------------------------------------------------------------
__global__ __launch_bounds__(256, 2)
void gemm_down(const _Float16* __restrict__ Hm,
               const _Float16* __restrict__ Wd,
               const float* __restrict__ dsc,
               float* __restrict__ out) {
    __shared__ _Float16 As0[128 * 64];   // k0..63   16KB
    __shared__ _Float16 As1[128 * 64];   // k64..127 16KB
    __shared__ _Float16 Bs0[128 * 64];
    __shared__ _Float16 Bs1[128 * 64];

    const int pid = (blockIdx.x % 8) * 64 + blockIdx.x / 8;
    const int loc = pid & 255;
    const int bm  = ((pid >> 8) * 16 + (loc & 15)) * 128;
    const int bn  = (loc >> 4) * 128;

    const int tid  = threadIdx.x;
    const int lane = tid & 63;
    const int wave = tid >> 6;
    const int wm   = (wave >> 1) * 64;
    const int wn   = (wave & 1) * 64;
    const int l15  = lane & 15;
    const int lq   = lane >> 4;

    int rS[4], sS[4];
    #pragma unroll
    for (int j = 0; j < 4; ++j) {
        const int f = tid + 256 * j;
        rS[j] = f >> 3;
        sS[j] = (((f & 7) - (f >> 3)) & 7) * 8;   // f16 elements, 16B segs
    }

    const _Float16* gA = Hm + (size_t)bm * INTER;
    const _Float16* gB = Wd + (size_t)bn * INTER;

    f32x4 acc[4][4] = {};

    for (int k0 = 0; k0 < INTER; k0 += BKD) {
        #pragma unroll
        for (int j = 0; j < 4; ++j) {
            const int f = tid + 256 * j;
            const size_t oA = (size_t)rS[j] * INTER + k0 + sS[j];
            GLDS16(gA + oA,      &As0[f * 8]);
            GLDS16(gA + oA + 64, &As1[f * 8]);
            GLDS16(gB + oA,      &Bs0[f * 8]);
            GLDS16(gB + oA + 64, &Bs1[f * 8]);
        }
        __syncthreads();

        #pragma unroll
        for (int ks = 0; ks < 4; ++ks) {
            const _Float16* A_ = (ks < 2) ? As0 : As1;
            const _Float16* B_ = (ks < 2) ? Bs0 : Bs1;
            const int q = (ks & 1) * 4 + lq;
            f16x8 a[4];
            #pragma unroll
            for (int im = 0; im < 4; ++im)
                a[im] = *(const f16x8*)&A_[swz8(wm + im * 16 + l15, q) * 8];
            #pragma unroll
            for (int jn = 0; jn < 4; ++jn) {
                f16x8 b = *(const f16x8*)&B_[swz8(wn + jn * 16 + l15, q) * 8];
                #pragma unroll
                for (int im = 0; im < 4; ++im)
                    acc[im][jn] = __builtin_amdgcn_mfma_f32_16x16x32_f16(a[im], b, acc[im][jn], 0, 0, 0);
            }
        }
        __syncthreads();
    }

    #pragma unroll
    for (int jn = 0; jn < 4; ++jn) {
        const int col = bn + wn + jn * 16 + l15;
        const float sd = dsc[col];
        #pragma unroll
        for (int im = 0; im < 4; ++im) {
            const int rbase = bm + wm + im * 16 + lq * 4;
            #pragma unroll
            for (int r = 0; r < 4; ++r)
                out[(size_t)(rbase + r) * HIDDEN + col] = acc[im][jn][r] * sd;
        }
    }
}

// ---------------------------------------------------------------------------
// launch — R9 MEASUREMENT: prepass launched 3x (idempotent).
//   dur_us - 371.2 = 2*(P + g)  ->  P = prepass duration, g = launch gap.
// Next round reverts to 1x and acts on the measured P.
// ---------------------------------------------------------------------------
extern "C" void kernel_launch(void* const* d_in, const int* in_sizes, int n_in,
                              void* d_out, int out_size, void* d_ws, size_t ws_size,
                              hipStream_t stream) {
    const float* x   = (const float*)d_in[0];
    const float* gw  = (const float*)d_in[1];
    const float* uw  = (const float*)d_in[2];
    const float* dw  = (const float*)d_in[3];
    const float* gsc = (const float*)d_in[4];
    const float* usc = (const float*)d_in[5];
    const float* dsc = (const float*)d_in[6];
    float* out = (float*)d_out;

    // workspace layout:
    //   Xq  i8  @          0 :  8,388,608
    //   Wg8 i8  @  8,388,608 : 11,534,336
    //   Wu8 i8  @ 19,922,944 : 11,534,336
    //   Wdh f16 @ 31,457,280 : 23,068,672
    //   Hm  f16 @ 54,525,952 : 46,137,344
    //   xs  f32 @100,663,296 :     16,384
    char* ws = (char*)d_ws;
    int8_t*   Xq  = (int8_t*)(ws);
    int8_t*   Wg8 = (int8_t*)(ws + 8388608ull);
    int8_t*   Wu8 = (int8_t*)(ws + 19922944ull);
    _Float16* Wdh = (_Float16*)(ws + 31457280ull);
    _Float16* Hm  = (_Float16*)(ws + 54525952ull);
    float*    xs  = (float*)(ws + 100663296ull);

    // 3x prepass: measurement (see header comment). Idempotent, bit-identical.
    for (int rep = 0; rep < 3; ++rep) {
        prepass<<<1024 + 2048, 256, 0, stream>>>(
            x, (const float4*)gw, (const float4*)uw, (const float4*)dw,
            Xq, xs, (int*)Wg8, (int*)Wu8, Wdh);
    }

    gemm_gateup<<<(INTER / 128) * (TOKENS / 128), 256, 0, stream>>>(
        Xq, Wg8, Wu8, xs, gsc, usc, Hm);
    gemm_down<<<(HIDDEN / 128) * (TOKENS / 128), 256, 0, stream>>>(
        Hm, Wdh, dsc, out);
}

// Round 10
// 362.780 us; speedup vs baseline: 1.2191x; 1.2191x over previous
//
#include <hip/hip_runtime.h>
#include <stdint.h>
#include <stddef.h>

#define HIDDEN 2048
#define INTER  5632
#define TOKENS 4096   // B*S = 2*2048
#define BKD    128    // f16 K-tile (down GEMM)  -> 2 half-tiles of 128B rows, 44 iters
#define BKI    128    // i8 K-tile (gateup GEMM) -> 128B rows, 16 iters
#define NT_GU  (HIDDEN / BKI)   // 16
#define NT_DN  (INTER / BKD)    // 44

typedef __attribute__((ext_vector_type(8))) _Float16 f16x8;
typedef __attribute__((ext_vector_type(4))) _Float16 f16x4;
typedef __attribute__((ext_vector_type(4))) float    f32x4;
typedef __attribute__((ext_vector_type(4))) int      i32x4;

// 128B-row LDS swizzle, period-8 row rotation: global segment q of row r lives
// at slot r*8 + ((q + r) & 7).  ds_read_b128 conflict unit is an 8-lane phase
// (8 x 16B = all 32 banks): fixed q -> 8 consecutive rows hit 8 DISTINCT
// bank-quads -> conflict-free (HW-verified: SQ_LDS_BANK_CONFLICT = 0, R0-R9).
__device__ __forceinline__ int swz8(int row, int q) {
    return row * 8 + ((q + row) & 7);
}

#define GLDS16(g, l) __builtin_amdgcn_global_load_lds( \
    (__attribute__((address_space(1))) void*)(g), \
    (__attribute__((address_space(3))) void*)(l), 16, 0, 0)

__device__ __forceinline__ int pack4i8(float4 f) {
    return ((int)(signed char)(int)f.x & 255)
         | (((int)(signed char)(int)f.y & 255) << 8)
         | (((int)(signed char)(int)f.z & 255) << 16)
         | (((int)(signed char)(int)f.w) << 24);
}

// ---------------------------------------------------------------------------
// fused prepass (R7 version, measured ~30-33us ~= its 35.6us BW roofline
// via the R9 3x-launch experiment; no further headroom).
// ---------------------------------------------------------------------------
__global__ __launch_bounds__(256)
void prepass(const float* __restrict__ x,
             const float4* __restrict__ gw, const float4* __restrict__ uw,
             const float4* __restrict__ dw,
             int8_t* __restrict__ xq, float* __restrict__ xs,
             int* __restrict__ go, int* __restrict__ uo,
             _Float16* __restrict__ dno) {
    const int tid = threadIdx.x;
    if (blockIdx.x < 1024) {
        const int wave = tid >> 6;
        const int lane = tid & 63;
        const int t    = blockIdx.x * 4 + wave;
        const float4* row = (const float4*)(x + (size_t)t * HIDDEN); // 512 f4
        float4 v[8];
        #pragma unroll
        for (int j = 0; j < 8; ++j) v[j] = row[lane + 64 * j];
        float m = 0.0f;
        #pragma unroll
        for (int j = 0; j < 8; ++j) {
            m = fmaxf(m, fmaxf(fmaxf(fabsf(v[j].x), fabsf(v[j].y)),
                               fmaxf(fabsf(v[j].z), fabsf(v[j].w))));
        }
        #pragma unroll
        for (int off = 32; off; off >>= 1)
            m = fmaxf(m, __shfl_xor(m, off, 64));
        m = fmaxf(m, 1e-20f);
        if (lane == 0) xs[t] = m * (1.0f / 127.0f);
        const float inv = 127.0f / m;
        int* oq = (int*)(xq + (size_t)t * HIDDEN);
        #pragma unroll
        for (int j = 0; j < 8; ++j) {
            float4 f = v[j];
            f.x *= inv; f.y *= inv; f.z *= inv; f.w *= inv;
            float4 r;
            r.x = rintf(f.x); r.y = rintf(f.y); r.z = rintf(f.z); r.w = rintf(f.w);
            oq[lane + 64 * j] = pack4i8(r);
        }
        return;
    }
    const int NA = INTER * HIDDEN / 16;   // 720896
    const int NC = INTER * HIDDEN / 8;    // 1441792
    const int stride = 2048 * 256;
    for (int u = (blockIdx.x - 1024) * 256 + tid; u < 2 * NA + NC; u += stride) {
        if (u < 2 * NA) {
            const bool is_g = u < NA;
            const int j = is_g ? u : u - NA;
            const float4* src = (is_g ? gw : uw) + (size_t)j * 4;
            float4 f0 = src[0], f1 = src[1], f2 = src[2], f3 = src[3];
            int4 p;
            p.x = pack4i8(f0); p.y = pack4i8(f1);
            p.z = pack4i8(f2); p.w = pack4i8(f3);
            ((int4*)(is_g ? go : uo))[j] = p;
        } else {
            const int j = u - 2 * NA;
            const float4* src = dw + (size_t)j * 2;
            float4 a = src[0], b = src[1];
            f16x8 o;
            o[0] = (_Float16)a.x; o[1] = (_Float16)a.y;
            o[2] = (_Float16)a.z; o[3] = (_Float16)a.w;
            o[4] = (_Float16)b.x; o[5] = (_Float16)b.y;
            o[6] = (_Float16)b.z; o[7] = (_Float16)b.w;
            *(f16x8*)(dno + (size_t)j * 8) = o;
        }
    }
}

// ---------------------------------------------------------------------------
// GEMM1 fused (i8): H = silu(G*xs*gs) * (U*xs*us)  (fp16 out)
// 128x128 tile, BKI=128, LDS 48KB SINGLE buffer, 2 blocks/CU.
// NEW (R10) read-all / stage-same-buffer schedule:
//   reads(all frags of tile t -> regs) ; sync#1 ; STAGE(t+1 -> SAME buf) ;
//   MFMA(regs) ; sync#2
// sync#2's vmcnt(0) drain now lands AFTER ~1300cyc of MFMA (R0 drained it
// before any compute).  Reads precede stage-issues in program order ->
// compiler cannot insert an aliasing vmcnt(0) before the ds_reads (the R3
// failure mode).  Same 2 barriers/iter, same LDS, same occupancy as R0.
// Frag regs: 128 acc + 96 frags + addr ~= 240 < 256 @ (256,2).
// ---------------------------------------------------------------------------
__global__ __launch_bounds__(256, 2)
void gemm_gateup(const int8_t* __restrict__ Xq,
                 const int8_t* __restrict__ Wg,
                 const int8_t* __restrict__ Wu,
                 const float* __restrict__ xs,
                 const float* __restrict__ gs,
                 const float* __restrict__ us,
                 _Float16* __restrict__ Hm) {
    __shared__ int8_t As [128 * BKI];
    __shared__ int8_t Bgs[128 * BKI];
    __shared__ int8_t Bus[128 * BKI];

    const int pid   = (blockIdx.x % 8) * 176 + blockIdx.x / 8;
    const int local = pid % (16 * 44);
    const int bm    = ((pid / (16 * 44)) * 16 + (local & 15)) * 128;
    const int bn    = (local >> 4) * 128;

    const int tid  = threadIdx.x;
    const int lane = tid & 63;
    const int wave = tid >> 6;
    const int wm   = (wave >> 1) * 64;
    const int wn   = (wave & 1) * 64;
    const int l15  = lane & 15;
    const int lq   = lane >> 4;

    int rowA[4], sgA[4];
    #pragma unroll
    for (int j = 0; j < 4; ++j) {
        const int f = tid + 256 * j;
        rowA[j] = f >> 3;
        sgA[j]  = (((f & 7) - rowA[j]) & 7) * 16;
    }

    #define STG_GU(k0) do { \
        _Pragma("unroll") \
        for (int j = 0; j < 4; ++j) { \
            const int f_ = tid + 256 * j; \
            const int8_t* pX = Xq + (size_t)(bm + rowA[j]) * HIDDEN + (k0) + sgA[j]; \
            const int8_t* pG = Wg + (size_t)(bn + rowA[j]) * HIDDEN + (k0) + sgA[j]; \
            const int8_t* pU = Wu + (size_t)(bn + rowA[j]) * HIDDEN + (k0) + sgA[j]; \
            GLDS16(pX, &As [f_ * 16]); \
            GLDS16(pG, &Bgs[f_ * 16]); \
            GLDS16(pU, &Bus[f_ * 16]); \
        } \
    } while (0)

    i32x4 accg[4][4] = {};
    i32x4 accu[4][4] = {};

    STG_GU(0);
    __syncthreads();

    for (int t = 0; t < NT_GU; ++t) {
        // ---- read ALL fragments of tile t into registers ----
        i32x4 a[2][4], bg[2][4], bu[2][4];
        #pragma unroll
        for (int ks = 0; ks < 2; ++ks) {
            const int q = ks * 4 + lq;
            #pragma unroll
            for (int im = 0; im < 4; ++im)
                a[ks][im] = *(const i32x4*)&As[swz8(wm + im * 16 + l15, q) * 16];
            #pragma unroll
            for (int jn = 0; jn < 4; ++jn) {
                bg[ks][jn] = *(const i32x4*)&Bgs[swz8(wn + jn * 16 + l15, q) * 16];
                bu[ks][jn] = *(const i32x4*)&Bus[swz8(wn + jn * 16 + l15, q) * 16];
            }
        }
        __syncthreads();                    // #1: all waves done reading
        if (t + 1 < NT_GU) STG_GU((t + 1) * BKI);   // same buffer
        #pragma unroll
        for (int ks = 0; ks < 2; ++ks)
            #pragma unroll
            for (int jn = 0; jn < 4; ++jn)
                #pragma unroll
                for (int im = 0; im < 4; ++im) {
                    accg[im][jn] = __builtin_amdgcn_mfma_i32_16x16x64_i8(a[ks][im], bg[ks][jn], accg[im][jn], 0, 0, 0);
                    accu[im][jn] = __builtin_amdgcn_mfma_i32_16x16x64_i8(a[ks][im], bu[ks][jn], accu[im][jn], 0, 0, 0);
                }
        __syncthreads();                    // #2: drain (after the MFMA block)
    }
    #undef STG_GU

    #pragma unroll
    for (int jn = 0; jn < 4; ++jn) {
        const int col = bn + wn + jn * 16 + l15;
        const float sg = gs[col];
        const float su = us[col];
        #pragma unroll
        for (int im = 0; im < 4; ++im) {
            const int rbase = bm + wm + im * 16 + lq * 4;
            #pragma unroll
            for (int r = 0; r < 4; ++r) {
                const int row = rbase + r;
                const float st = xs[row];
                float g = (float)accg[im][jn][r] * st * sg;
                float u = (float)accu[im][jn][r] * st * su;
                float h = (g / (1.0f + __expf(-g))) * u;
                Hm[(size_t)row * INTER + col] = (_Float16)h;
            }
        }
    }
}

// ---------------------------------------------------------------------------
// GEMM2 (fp16): out = (H @ Wd^T) * down_s  (fp32 out)
// 128x128 tile, BKD=128 (two swz8 half-tiles per matrix), LDS 64KB SINGLE
// buffer, 2 blocks/CU.  Same R10 read-all / stage-same-buffer schedule.
// Frag regs: 64 acc + 128 frags + addr ~= 210 < 256 @ (256,2).
// ---------------------------------------------------------------------------
__global__ __launch_bounds__(256, 2)
void gemm_down(const _Float16* __restrict__ Hm,
               const _Float16* __restrict__ Wd,
               const float* __restrict__ dsc,
               float* __restrict__ out) {
    __shared__ _Float16 As0[128 * 64];   // k0..63   16KB
    __shared__ _Float16 As1[128 * 64];   // k64..127 16KB
    __shared__ _Float16 Bs0[128 * 64];
    __shared__ _Float16 Bs1[128 * 64];

    const int pid = (blockIdx.x % 8) * 64 + blockIdx.x / 8;
    const int loc = pid & 255;
    const int bm  = ((pid >> 8) * 16 + (loc & 15)) * 128;
    const int bn  = (loc >> 4) * 128;

    const int tid  = threadIdx.x;
    const int lane = tid & 63;
    const int wave = tid >> 6;
    const int wm   = (wave >> 1) * 64;
    const int wn   = (wave & 1) * 64;
    const int l15  = lane & 15;
    const int lq   = lane >> 4;

    int rS[4], sS[4];
    #pragma unroll
    for (int j = 0; j < 4; ++j) {
        const int f = tid + 256 * j;
        rS[j] = f >> 3;
        sS[j] = (((f & 7) - (f >> 3)) & 7) * 8;   // f16 elements, 16B segs
    }

    const _Float16* gA = Hm + (size_t)bm * INTER;
    const _Float16* gB = Wd + (size_t)bn * INTER;

    #define STG_DN(k0) do { \
        _Pragma("unroll") \
        for (int j = 0; j < 4; ++j) { \
            const int f_ = tid + 256 * j; \
            const size_t o_ = (size_t)rS[j] * INTER + (k0) + sS[j]; \
            GLDS16(gA + o_,      &As0[f_ * 8]); \
            GLDS16(gA + o_ + 64, &As1[f_ * 8]); \
            GLDS16(gB + o_,      &Bs0[f_ * 8]); \
            GLDS16(gB + o_ + 64, &Bs1[f_ * 8]); \
        } \
    } while (0)

    f32x4 acc[4][4] = {};

    STG_DN(0);
    __syncthreads();

    for (int t = 0; t < NT_DN; ++t) {
        // ---- read ALL fragments of tile t into registers ----
        f16x8 a[4][4], b[4][4];             // [ks][im] / [ks][jn]
        #pragma unroll
        for (int ks = 0; ks < 4; ++ks) {
            const _Float16* A_ = (ks < 2) ? As0 : As1;
            const _Float16* B_ = (ks < 2) ? Bs0 : Bs1;
            const int q = (ks & 1) * 4 + lq;
            #pragma unroll
            for (int im = 0; im < 4; ++im)
                a[ks][im] = *(const f16x8*)&A_[swz8(wm + im * 16 + l15, q) * 8];
            #pragma unroll
            for (int jn = 0; jn < 4; ++jn)
                b[ks][jn] = *(const f16x8*)&B_[swz8(wn + jn * 16 + l15, q) * 8];
        }
        __syncthreads();                    // #1: all waves done reading
        if (t + 1 < NT_DN) STG_DN((t + 1) * BKD);   // same buffers
        #pragma unroll
        for (int ks = 0; ks < 4; ++ks)
            #pragma unroll
            for (int jn = 0; jn < 4; ++jn)
                #pragma unroll
                for (int im = 0; im < 4; ++im)
                    acc[im][jn] = __builtin_amdgcn_mfma_f32_16x16x32_f16(a[ks][im], b[ks][jn], acc[im][jn], 0, 0, 0);
        __syncthreads();                    // #2: drain (after the MFMA block)
    }
    #undef STG_DN

    #pragma unroll
    for (int jn = 0; jn < 4; ++jn) {
        const int col = bn + wn + jn * 16 + l15;
        const float sd = dsc[col];
        #pragma unroll
        for (int im = 0; im < 4; ++im) {
            const int rbase = bm + wm + im * 16 + lq * 4;
            #pragma unroll
            for (int r = 0; r < 4; ++r)
                out[(size_t)(rbase + r) * HIDDEN + col] = acc[im][jn][r] * sd;
        }
    }
}

// ---------------------------------------------------------------------------
// launch
// ---------------------------------------------------------------------------
extern "C" void kernel_launch(void* const* d_in, const int* in_sizes, int n_in,
                              void* d_out, int out_size, void* d_ws, size_t ws_size,
                              hipStream_t stream) {
    const float* x   = (const float*)d_in[0];
    const float* gw  = (const float*)d_in[1];
    const float* uw  = (const float*)d_in[2];
    const float* dw  = (const float*)d_in[3];
    const float* gsc = (const float*)d_in[4];
    const float* usc = (const float*)d_in[5];
    const float* dsc = (const float*)d_in[6];
    float* out = (float*)d_out;

    // workspace layout:
    //   Xq  i8  @          0 :  8,388,608
    //   Wg8 i8  @  8,388,608 : 11,534,336
    //   Wu8 i8  @ 19,922,944 : 11,534,336
    //   Wdh f16 @ 31,457,280 : 23,068,672
    //   Hm  f16 @ 54,525,952 : 46,137,344
    //   xs  f32 @100,663,296 :     16,384
    char* ws = (char*)d_ws;
    int8_t*   Xq  = (int8_t*)(ws);
    int8_t*   Wg8 = (int8_t*)(ws + 8388608ull);
    int8_t*   Wu8 = (int8_t*)(ws + 19922944ull);
    _Float16* Wdh = (_Float16*)(ws + 31457280ull);
    _Float16* Hm  = (_Float16*)(ws + 54525952ull);
    float*    xs  = (float*)(ws + 100663296ull);

    prepass<<<1024 + 2048, 256, 0, stream>>>(
        x, (const float4*)gw, (const float4*)uw, (const float4*)dw,
        Xq, xs, (int*)Wg8, (int*)Wu8, Wdh);

    gemm_gateup<<<(INTER / 128) * (TOKENS / 128), 256, 0, stream>>>(
        Xq, Wg8, Wu8, xs, gsc, usc, Hm);
    gemm_down<<<(HIDDEN / 128) * (TOKENS / 128), 256, 0, stream>>>(
        Hm, Wdh, dsc, out);
}